// Round 1
// baseline (767.984 us; speedup 1.0000x reference)
//
#include <hip/hip_runtime.h>
#include <stdint.h>

// ---------------------------------------------------------------------------
// MultiGraph hetero-GNN + gumbel-top-k edge pruning, fp32 throughout.
// JAX PRNG (threefry2x32) reproduced bit-exactly; partitionable path (modern
// JAX default). Flip JAX_PARTITIONABLE to 0 if w_pp/w_aa come back wrong.
// ---------------------------------------------------------------------------
#define JAX_PARTITIONABLE 1

namespace {

constexpr int NPn = 4096;
constexpr int NAn = 2048;
constexpr int Hh  = 128;
constexpr int EPPc = 131072;
constexpr int EAAc = 65536;
constexpr int EPAc = 131072;
constexpr int EAPc = 131072;
constexpr int KSEL = 5;

// CSR order: 0 pp-by-dst, 1 aa-by-dst, 2 pa-by-dst, 3 ap-by-dst, 4 pp-by-src, 5 aa-by-src
// cnt/cursor offsets (ints)
// pp-d:0(4096) aa-d:4096(2048) pa-d:6144(2048) ap-d:8192(4096) pp-s:12288(4096) aa-s:16384(2048)
// rowptr offsets: 0,4097,6146,8195,12292,16389 (each N+1)
// entries offsets: 0,131072,196608,327680,458752,589824 (total 655360)

__host__ __device__ static inline void tf2x32(uint32_t k0, uint32_t k1,
                                              uint32_t& x0, uint32_t& x1) {
  uint32_t ks2 = k0 ^ k1 ^ 0x1BD11BDAu;
  x0 += k0; x1 += k1;
#define TF_R(r) { x0 += x1; x1 = (x1 << (r)) | (x1 >> (32 - (r))); x1 ^= x0; }
  TF_R(13) TF_R(15) TF_R(26) TF_R(6)
  x0 += k1;  x1 += ks2 + 1u;
  TF_R(17) TF_R(29) TF_R(16) TF_R(24)
  x0 += ks2; x1 += k0 + 2u;
  TF_R(13) TF_R(15) TF_R(26) TF_R(6)
  x0 += k0;  x1 += k1 + 3u;
  TF_R(17) TF_R(29) TF_R(16) TF_R(24)
  x0 += k1;  x1 += ks2 + 4u;
  TF_R(13) TF_R(15) TF_R(26) TF_R(6)
  x0 += ks2; x1 += k0 + 5u;
#undef TF_R
}

// ---------------- CSR build ----------------
__global__ __launch_bounds__(256) void hist_kernel(
    const int* d0, const int* d1, const int* d2, const int* d3,
    const int* d4, const int* d5, int* cnt)
{
  int i = blockIdx.x * 256 + threadIdx.x;
  const int* kp; int co, e;
  if      (i < 131072) { kp = d0; co = 0;     e = i; }
  else if (i < 196608) { kp = d1; co = 4096;  e = i - 131072; }
  else if (i < 327680) { kp = d2; co = 6144;  e = i - 196608; }
  else if (i < 458752) { kp = d3; co = 8192;  e = i - 327680; }
  else if (i < 589824) { kp = d4; co = 12288; e = i - 458752; }
  else if (i < 655360) { kp = d5; co = 16384; e = i - 589824; }
  else return;
  atomicAdd(&cnt[co + kp[e]], 1);
}

__global__ __launch_bounds__(1024) void scan_kernel(const int* cnt, int* rowptr, int* cursor)
{
  __shared__ int buf[1024];
  const int Ns[6]   = {4096, 2048, 2048, 4096, 4096, 2048};
  const int coff[6] = {0, 4096, 6144, 8192, 12288, 16384};
  const int roff[6] = {0, 4097, 6146, 8195, 12292, 16389};
  int rel = blockIdx.x, tid = threadIdx.x;
  int N = Ns[rel], co = coff[rel], ro = roff[rel];
  int carry = 0;
  for (int base = 0; base < N; base += 1024) {
    int v = cnt[co + base + tid];
    buf[tid] = v; __syncthreads();
    for (int s = 1; s < 1024; s <<= 1) {
      int t = (tid >= s) ? buf[tid - s] : 0;
      __syncthreads();
      buf[tid] += t;
      __syncthreads();
    }
    int excl = carry + buf[tid] - v;
    rowptr[ro + base + tid] = excl;
    cursor[co + base + tid] = excl;
    carry += buf[1023];
    __syncthreads();
  }
  if (tid == 0) rowptr[ro + N] = carry;
}

__global__ __launch_bounds__(256) void scatter_kernel(
    const int* d0, const int* d1, const int* d2, const int* d3,
    const int* d4, const int* d5, int* cursor, int* entries)
{
  int i = blockIdx.x * 256 + threadIdx.x;
  const int* kp; int co, eo, e;
  if      (i < 131072) { kp = d0; co = 0;     eo = 0;      e = i; }
  else if (i < 196608) { kp = d1; co = 4096;  eo = 131072; e = i - 131072; }
  else if (i < 327680) { kp = d2; co = 6144;  eo = 196608; e = i - 196608; }
  else if (i < 458752) { kp = d3; co = 8192;  eo = 327680; e = i - 327680; }
  else if (i < 589824) { kp = d4; co = 12288; eo = 458752; e = i - 458752; }
  else if (i < 655360) { kp = d5; co = 16384; eo = 589824; e = i - 589824; }
  else return;
  int pos = atomicAdd(&cursor[co + kp[e]], 1);
  entries[eo + pos] = e;
}

// ---------------- mean aggregation (per-dst): M[d] = sum(w_e * h[src_e]) / max(deg,1) ----
__global__ __launch_bounds__(256) void agg_kernel(
    const float* __restrict__ h, const int* __restrict__ srcArr,
    const int* __restrict__ ent, const int* __restrict__ rp,
    const float* __restrict__ w, float* __restrict__ M, int Ndst)
{
  int node = blockIdx.x * 4 + (threadIdx.x >> 6);
  int lane = threadIdx.x & 63;
  if (node >= Ndst) return;
  int b = rp[node], e = rp[node + 1];
  float ax = 0.f, ay = 0.f;
  for (int k = b; k < e; ++k) {
    int ed = ent[k];
    int s = srcArr[ed];
    float wt = w ? w[ed] : 1.0f;
    float2 v = *(const float2*)&h[s * Hh + lane * 2];
    ax += wt * v.x; ay += wt * v.y;
  }
  float cd = fmaxf((float)(e - b), 1.0f);
  float2 o; o.x = ax / cd; o.y = ay / cd;
  *(float2*)&M[node * Hh + lane * 2] = o;
}

// ---------------- multi-part fp32 GEMM: C = act(sum_p A_p[M,128] @ W_p[128,N]) ----------
__global__ __launch_bounds__(256) void gemm_mp(
    const float* __restrict__ A0, const float* __restrict__ W0,
    const float* __restrict__ A1, const float* __restrict__ W1,
    const float* __restrict__ A2, const float* __restrict__ W2,
    int nparts, float* __restrict__ C, int M, int N, int doRelu)
{
  __shared__ __align__(16) float As[32][68];  // [k][m]
  __shared__ __align__(16) float Ws[32][68];  // [k][n]
  int nTiles = N >> 6;
  int bx = blockIdx.x % nTiles;
  int by = blockIdx.x / nTiles;
  int m0 = by << 6, n0 = bx << 6;
  int tid = threadIdx.x;
  int tr = tid >> 4, tc = tid & 15;
  int r = tid >> 3, f = tid & 7;
  float acc[4][4] = {{0.f}};
  const float* Ap[3] = {A0, A1, A2};
  const float* Wp[3] = {W0, W1, W2};
  for (int pi = 0; pi < nparts; ++pi) {
    const float* A = Ap[pi]; const float* W = Wp[pi];
    for (int k0 = 0; k0 < 128; k0 += 32) {
      float4 va0 = *(const float4*)&A[(size_t)(m0 + r) * 128 + k0 + f * 4];
      float4 va1 = *(const float4*)&A[(size_t)(m0 + r + 32) * 128 + k0 + f * 4];
      float4 vw0 = *(const float4*)&W[(size_t)(k0 + r) * N + n0 + f * 4];
      float4 vw1 = *(const float4*)&W[(size_t)(k0 + r) * N + n0 + f * 4 + 32];
      __syncthreads();
      As[f * 4 + 0][r] = va0.x; As[f * 4 + 1][r] = va0.y;
      As[f * 4 + 2][r] = va0.z; As[f * 4 + 3][r] = va0.w;
      As[f * 4 + 0][r + 32] = va1.x; As[f * 4 + 1][r + 32] = va1.y;
      As[f * 4 + 2][r + 32] = va1.z; As[f * 4 + 3][r + 32] = va1.w;
      *(float4*)&Ws[r][f * 4] = vw0;
      *(float4*)&Ws[r][f * 4 + 32] = vw1;
      __syncthreads();
#pragma unroll
      for (int k = 0; k < 32; ++k) {
        float4 a = *(const float4*)&As[k][tr * 4];
        float4 b = *(const float4*)&Ws[k][tc * 4];
        acc[0][0] += a.x * b.x; acc[0][1] += a.x * b.y; acc[0][2] += a.x * b.z; acc[0][3] += a.x * b.w;
        acc[1][0] += a.y * b.x; acc[1][1] += a.y * b.y; acc[1][2] += a.y * b.z; acc[1][3] += a.y * b.w;
        acc[2][0] += a.z * b.x; acc[2][1] += a.z * b.y; acc[2][2] += a.z * b.z; acc[2][3] += a.z * b.w;
        acc[3][0] += a.w * b.x; acc[3][1] += a.w * b.y; acc[3][2] += a.w * b.z; acc[3][3] += a.w * b.w;
      }
    }
  }
#pragma unroll
  for (int i = 0; i < 4; ++i) {
    float4 v;
    v.x = acc[i][0]; v.y = acc[i][1]; v.z = acc[i][2]; v.w = acc[i][3];
    if (doRelu) {
      v.x = fmaxf(v.x, 0.f); v.y = fmaxf(v.y, 0.f);
      v.z = fmaxf(v.z, 0.f); v.w = fmaxf(v.w, 0.f);
    }
    *(float4*)&C[(size_t)(m0 + tr * 4 + i) * N + n0 + tc * 4] = v;
  }
}

// ---------------- edge predictor: pred[e] = relu(P1[src]+P2[dst]+b1) . Wep2[:,0] + b2[0] --
__global__ __launch_bounds__(256) void edge_pred(
    const float* __restrict__ P1, const float* __restrict__ P2,
    const int* __restrict__ src, const int* __restrict__ dst,
    const float* __restrict__ bep1, const float* __restrict__ Wep2,
    const float* __restrict__ bep2, float* __restrict__ pred, int E)
{
  int e = blockIdx.x * 4 + (threadIdx.x >> 6);
  int lane = threadIdx.x & 63;
  if (e >= E) return;
  int s = src[e], d = dst[e];
  float4 a  = *(const float4*)&P1[(size_t)s * 256 + lane * 4];
  float4 b  = *(const float4*)&P2[(size_t)d * 256 + lane * 4];
  float4 bb = *(const float4*)&bep1[lane * 4];
  int j = lane * 4;
  float t0 = fmaxf(a.x + b.x + bb.x, 0.f);
  float t1 = fmaxf(a.y + b.y + bb.y, 0.f);
  float t2 = fmaxf(a.z + b.z + bb.z, 0.f);
  float t3 = fmaxf(a.w + b.w + bb.w, 0.f);
  float sum = t0 * Wep2[(j + 0) * 2] + t1 * Wep2[(j + 1) * 2] +
              t2 * Wep2[(j + 2) * 2] + t3 * Wep2[(j + 3) * 2];
  for (int off = 32; off; off >>= 1) sum += __shfl_down(sum, off);
  if (lane == 0) pred[e] = sum + bep2[0];
}

// ---------------- per-row masked gumbel top-5 -------------------------------------------
__global__ __launch_bounds__(256) void row_topk(
    const float* __restrict__ pred_pp, const float* __restrict__ pred_aa,
    const int* __restrict__ dst_pp, const int* __restrict__ dst_aa,
    const int* __restrict__ rp_pps, const int* __restrict__ ent_pps,
    const int* __restrict__ rp_aas, const int* __restrict__ ent_aas,
    int* __restrict__ S_sel,
    uint32_t kpp0, uint32_t kpp1, uint32_t kaa0, uint32_t kaa1)
{
  __shared__ float ys[4096];
  __shared__ float redv[256];
  __shared__ int   redc[256];
  int b = blockIdx.x, tid = threadIdx.x;
  int row, Ncols, selbase; const float* pred; const int* dst;
  const int* rp; const int* ent; uint32_t k0, k1;
  if (b < NPn) {
    row = b; Ncols = NPn; pred = pred_pp; dst = dst_pp;
    rp = rp_pps; ent = ent_pps; k0 = kpp0; k1 = kpp1; selbase = 0;
  } else {
    row = b - NPn; Ncols = NAn; pred = pred_aa; dst = dst_aa;
    rp = rp_aas; ent = ent_aas; k0 = kaa0; k1 = kaa1; selbase = NPn * KSEL;
  }
  for (int c = tid; c < Ncols; c += 256) ys[c] = 0.f;
  __syncthreads();
  int beg = rp[row], end = rp[row + 1];
  for (int k = beg + tid; k < end; k += 256) {
    int e = ent[k];
    atomicAdd(&ys[dst[e]], pred[e]);  // coalesce duplicate (src,dst) by sum
  }
  __syncthreads();
  uint32_t rowbase = (uint32_t)row * (uint32_t)Ncols;
  for (int c = tid; c < Ncols; c += 256) {
    float a = ys[c];
    float y = -1e9f;
    if (a > 0.f) {
      uint32_t j = rowbase + (uint32_t)c;
      uint32_t x0, x1, bits;
#if JAX_PARTITIONABLE
      x0 = 0u; x1 = j;
      tf2x32(k0, k1, x0, x1);
      bits = x0 ^ x1;
#else
      uint32_t halfE = (Ncols == NPn) ? 8388608u : 2097152u;
      if (j < halfE) { x0 = j; x1 = j + halfE; } else { x0 = j - halfE; x1 = j; }
      tf2x32(k0, k1, x0, x1);
      bits = (j < halfE) ? x0 : x1;
#endif
      // jax.random.uniform(minval=1e-10, maxval=1.0) bit path
      float fl = __uint_as_float((bits >> 9) | 0x3f800000u) - 1.0f;
      float u = fmaxf(1e-10f, fl + 1e-10f);
      float g = -logf(-logf(u));
      y = a + g;  // tau == 1.0
    }
    ys[c] = y;
  }
  __syncthreads();
  for (int it = 0; it < KSEL; ++it) {
    float best = -3.4e38f; int bcol = 0x7fffffff;
    for (int c = tid; c < Ncols; c += 256) {
      float v = ys[c];
      if (v > best) { best = v; bcol = c; }  // ascending c: ties keep lower index
    }
    redv[tid] = best; redc[tid] = bcol;
    __syncthreads();
    for (int s = 128; s; s >>= 1) {
      if (tid < s) {
        float v2 = redv[tid + s]; int c2 = redc[tid + s];
        if (v2 > redv[tid] || (v2 == redv[tid] && c2 < redc[tid])) {
          redv[tid] = v2; redc[tid] = c2;
        }
      }
      __syncthreads();
    }
    if (tid == 0) {
      S_sel[selbase + row * KSEL + it] = redc[0];
      ys[redc[0]] = -3.0e38f;  // below masked sentinel: never re-picked
    }
    __syncthreads();
  }
}

// ---------------- gather hard 0/1 weights back onto edges -------------------------------
__global__ __launch_bounds__(256) void w_gather(
    const int* __restrict__ src_pp, const int* __restrict__ dst_pp,
    const int* __restrict__ src_aa, const int* __restrict__ dst_aa,
    const int* __restrict__ S_sel, float* __restrict__ w_pp, float* __restrict__ w_aa)
{
  int i = blockIdx.x * 256 + threadIdx.x;
  if (i < EPPc) {
    int s = src_pp[i], d = dst_pp[i];
    const int* sel = S_sel + s * KSEL;
    float v = 0.f;
#pragma unroll
    for (int k = 0; k < KSEL; ++k) v = (sel[k] == d) ? 1.f : v;
    w_pp[i] = v;
  } else {
    int j = i - EPPc;
    int s = src_aa[j], d = dst_aa[j];
    const int* sel = S_sel + NPn * KSEL + s * KSEL;
    float v = 0.f;
#pragma unroll
    for (int k = 0; k < KSEL; ++k) v = (sel[k] == d) ? 1.f : v;
    w_aa[j] = v;
  }
}

// ---------------- fused GNN2-layer1 (single row) + classifier ---------------------------
__global__ __launch_bounds__(128) void final_kernel(
    const float* __restrict__ hp, const float* __restrict__ ha,
    const int* __restrict__ idxPtr,
    const int* __restrict__ src_pp, const float* __restrict__ wpp,
    const int* __restrict__ rp_ppd, const int* __restrict__ ent_ppd,
    const int* __restrict__ src_ap,
    const int* __restrict__ rp_apd, const int* __restrict__ ent_apd,
    const float* __restrict__ Wself, const float* __restrict__ Wpp,
    const float* __restrict__ Wap,
    const float* __restrict__ Wc, const float* __restrict__ bc,
    float* __restrict__ out)
{
  __shared__ float selfr[128], mpp[128], mapr[128], t[128];
  int tid = threadIdx.x;
  int idx = idxPtr[0];
  selfr[tid] = hp[(size_t)idx * 128 + tid];
  {
    int b = rp_ppd[idx], e2 = rp_ppd[idx + 1];
    float acc = 0.f;
    for (int k = b; k < e2; ++k) {
      int ed = ent_ppd[k];
      acc += wpp[ed] * hp[(size_t)src_pp[ed] * 128 + tid];
    }
    mpp[tid] = acc / fmaxf((float)(e2 - b), 1.0f);
  }
  {
    int b = rp_apd[idx], e2 = rp_apd[idx + 1];
    float acc = 0.f;
    for (int k = b; k < e2; ++k) {
      int ed = ent_apd[k];
      acc += ha[(size_t)src_ap[ed] * 128 + tid];
    }
    mapr[tid] = acc / fmaxf((float)(e2 - b), 1.0f);
  }
  __syncthreads();
  float s = 0.f;
  for (int m = 0; m < 128; ++m) {
    s += selfr[m] * Wself[m * 128 + tid] + mpp[m] * Wpp[m * 128 + tid] +
         mapr[m] * Wap[m * 128 + tid];
  }
  t[tid] = fmaxf(s, 0.f);
  __syncthreads();
  if (tid < 5) {
    float y = bc[tid];
    for (int k = 0; k < 128; ++k) y += t[k] * Wc[k * 5 + tid];
    out[tid] = y;
  }
}

}  // namespace

extern "C" void kernel_launch(void* const* d_in, const int* in_sizes, int n_in,
                              void* d_out, int out_size, void* d_ws, size_t ws_size,
                              hipStream_t stream)
{
  (void)in_sizes; (void)n_in; (void)out_size; (void)ws_size;
  const float* x_p = (const float*)d_in[0];
  const float* x_a = (const float*)d_in[1];
  const int* ei_pp = (const int*)d_in[2];
  const int* ei_aa = (const int*)d_in[3];
  const int* ei_pa = (const int*)d_in[4];
  const int* ei_ap = (const int*)d_in[5];
  const int* idxPtr = (const int*)d_in[8];
  const float* Wself_p0 = (const float*)d_in[9];
  const float* Wself_p1 = (const float*)d_in[10];
  const float* Wself_a0 = (const float*)d_in[11];
  const float* Wself_a1 = (const float*)d_in[12];
  const float* Wpp0 = (const float*)d_in[13]; const float* Wpp1 = (const float*)d_in[14];
  const float* Waa0 = (const float*)d_in[15]; const float* Waa1 = (const float*)d_in[16];
  const float* Wpa0 = (const float*)d_in[17]; /* Wpa1 unused: author L1 dropped */
  const float* Wap0 = (const float*)d_in[19]; const float* Wap1 = (const float*)d_in[20];
  const float* Wep1_pp = (const float*)d_in[21]; const float* bep1_pp = (const float*)d_in[22];
  const float* Wep2_pp = (const float*)d_in[23]; const float* bep2_pp = (const float*)d_in[24];
  const float* Wep1_aa = (const float*)d_in[25]; const float* bep1_aa = (const float*)d_in[26];
  const float* Wep2_aa = (const float*)d_in[27]; const float* bep2_aa = (const float*)d_in[28];
  const float* Wc = (const float*)d_in[29]; const float* bc = (const float*)d_in[30];

  float* out = (float*)d_out;
  float* w_pp_out = out + 5;
  float* w_aa_out = out + 5 + EPPc;

  const int* src_pp = ei_pp;  const int* dst_pp = ei_pp + EPPc;
  const int* src_aa = ei_aa;  const int* dst_aa = ei_aa + EAAc;
  const int* src_pa = ei_pa;  const int* dst_pa = ei_pa + EPAc;
  const int* src_ap = ei_ap;  const int* dst_ap = ei_ap + EAPc;

  // ---- workspace layout (bump allocator; cnt MUST be first: it gets memset) ----
  char* p = (char*)d_ws;
  auto alloc = [&](size_t bytes) -> void* {
    void* r = (void*)p;
    p += (bytes + 255) & ~(size_t)255;
    return r;
  };
  int* cnt     = (int*)alloc(18432 * sizeof(int));
  int* rowptr  = (int*)alloc(18438 * sizeof(int));
  int* cursor  = (int*)alloc(18432 * sizeof(int));
  int* entries = (int*)alloc(655360 * sizeof(int));
  int* S_sel   = (int*)alloc((size_t)(NPn + NAn) * KSEL * sizeof(int));
  float* pred_pp = (float*)alloc((size_t)EPPc * sizeof(float));
  float* pred_aa = (float*)alloc((size_t)EAAc * sizeof(float));
  float* Mpp  = (float*)alloc((size_t)NPn * Hh * sizeof(float));
  float* Maa  = (float*)alloc((size_t)NAn * Hh * sizeof(float));
  float* Mpa  = (float*)alloc((size_t)NAn * Hh * sizeof(float));
  float* Map  = (float*)alloc((size_t)NPn * Hh * sizeof(float));
  float* h1p0 = (float*)alloc((size_t)NPn * Hh * sizeof(float));
  float* h1a0 = (float*)alloc((size_t)NAn * Hh * sizeof(float));
  float* h1p1 = (float*)alloc((size_t)NPn * Hh * sizeof(float));
  float* h1a1 = (float*)alloc((size_t)NAn * Hh * sizeof(float));
  float* h2p0 = (float*)alloc((size_t)NPn * Hh * sizeof(float));
  float* h2a0 = (float*)alloc((size_t)NAn * Hh * sizeof(float));
  float* P1pp = (float*)alloc((size_t)NPn * 256 * sizeof(float));
  float* P2pp = (float*)alloc((size_t)NPn * 256 * sizeof(float));
  float* P1aa = (float*)alloc((size_t)NAn * 256 * sizeof(float));
  float* P2aa = (float*)alloc((size_t)NAn * 256 * sizeof(float));

  // rowptr / entries offsets per CSR
  const int RP_PPD = 0, RP_AAD = 4097, RP_PAD = 6146, RP_APD = 8195,
            RP_PPS = 12292, RP_AAS = 16389;
  const int EN_PPD = 0, EN_AAD = 131072, EN_PAD = 196608, EN_APD = 327680,
            EN_PPS = 458752, EN_AAS = 589824;

  hipMemsetAsync(cnt, 0, 18432 * sizeof(int), stream);
  hist_kernel<<<2560, 256, 0, stream>>>(dst_pp, dst_aa, dst_pa, dst_ap, src_pp, src_aa, cnt);
  scan_kernel<<<6, 1024, 0, stream>>>(cnt, rowptr, cursor);
  scatter_kernel<<<2560, 256, 0, stream>>>(dst_pp, dst_aa, dst_pa, dst_ap, src_pp, src_aa,
                                           cursor, entries);

  auto agg = [&](const float* h, const int* srcArr, int enOff, int rpOff,
                 const float* w, float* M, int Ndst) {
    agg_kernel<<<Ndst / 4, 256, 0, stream>>>(h, srcArr, entries + enOff, rowptr + rpOff,
                                             w, M, Ndst);
  };
  auto gemm = [&](const float* A0, const float* W0, const float* A1, const float* W1,
                  const float* A2, const float* W2, int nparts, float* C, int M, int N,
                  int relu) {
    gemm_mp<<<(M / 64) * (N / 64), 256, 0, stream>>>(A0, W0, A1, W1, A2, W2, nparts, C,
                                                     M, N, relu);
  };

  // ---- GNN1 (single=True: pp, aa only) ----
  agg(x_p, src_pp, EN_PPD, RP_PPD, nullptr, Mpp, NPn);
  agg(x_a, src_aa, EN_AAD, RP_AAD, nullptr, Maa, NAn);
  gemm(x_p, Wself_p0, Mpp, Wpp0, nullptr, nullptr, 2, h1p0, NPn, 128, 1);
  gemm(x_a, Wself_a0, Maa, Waa0, nullptr, nullptr, 2, h1a0, NAn, 128, 1);
  agg(h1p0, src_pp, EN_PPD, RP_PPD, nullptr, Mpp, NPn);
  agg(h1a0, src_aa, EN_AAD, RP_AAD, nullptr, Maa, NAn);
  gemm(h1p0, Wself_p1, Mpp, Wpp1, nullptr, nullptr, 2, h1p1, NPn, 128, 1);
  gemm(h1a0, Wself_a1, Maa, Waa1, nullptr, nullptr, 2, h1a1, NAn, 128, 1);

  // ---- edge MLP via P-split: concat(h_s,h_d)@Wep1 == P1[s] + P2[d] ----
  gemm(h1p1, Wep1_pp,             nullptr, nullptr, nullptr, nullptr, 1, P1pp, NPn, 256, 0);
  gemm(h1p1, Wep1_pp + 128 * 256, nullptr, nullptr, nullptr, nullptr, 1, P2pp, NPn, 256, 0);
  gemm(h1a1, Wep1_aa,             nullptr, nullptr, nullptr, nullptr, 1, P1aa, NAn, 256, 0);
  gemm(h1a1, Wep1_aa + 128 * 256, nullptr, nullptr, nullptr, nullptr, 1, P2aa, NAn, 256, 0);
  edge_pred<<<EPPc / 4, 256, 0, stream>>>(P1pp, P2pp, src_pp, dst_pp, bep1_pp, Wep2_pp,
                                          bep2_pp, pred_pp, EPPc);
  edge_pred<<<EAAc / 4, 256, 0, stream>>>(P1aa, P2aa, src_aa, dst_aa, bep1_aa, Wep2_aa,
                                          bep2_aa, pred_aa, EAAc);

  // ---- JAX keys: key(42) -> split -> (kpp, kaa), computed host-side ----
  uint32_t kpp0, kpp1, kaa0, kaa1;
#if JAX_PARTITIONABLE
  { uint32_t a0 = 0, a1 = 0; tf2x32(0u, 42u, a0, a1); kpp0 = a0; kpp1 = a1; }
  { uint32_t a0 = 0, a1 = 1; tf2x32(0u, 42u, a0, a1); kaa0 = a0; kaa1 = a1; }
#else
  { uint32_t a0 = 0, a1 = 2, b0 = 1, b1 = 3;
    tf2x32(0u, 42u, a0, a1); tf2x32(0u, 42u, b0, b1);
    kpp0 = a0; kpp1 = b0; kaa0 = a1; kaa1 = b1; }
#endif

  row_topk<<<NPn + NAn, 256, 0, stream>>>(pred_pp, pred_aa, dst_pp, dst_aa,
                                          rowptr + RP_PPS, entries + EN_PPS,
                                          rowptr + RP_AAS, entries + EN_AAS,
                                          S_sel, kpp0, kpp1, kaa0, kaa1);
  w_gather<<<(EPPc + EAAc) / 256, 256, 0, stream>>>(src_pp, dst_pp, src_aa, dst_aa, S_sel,
                                                    w_pp_out, w_aa_out);

  // ---- GNN2 layer 0 (all relations; pp/aa with hard attention weights) ----
  agg(x_p, src_pp, EN_PPD, RP_PPD, w_pp_out, Mpp, NPn);
  agg(x_a, src_ap, EN_APD, RP_APD, nullptr,  Map, NPn);
  agg(x_a, src_aa, EN_AAD, RP_AAD, w_aa_out, Maa, NAn);
  agg(x_p, src_pa, EN_PAD, RP_PAD, nullptr,  Mpa, NAn);
  gemm(x_p, Wself_p0, Mpp, Wpp0, Map, Wap0, 3, h2p0, NPn, 128, 1);
  gemm(x_a, Wself_a0, Maa, Waa0, Mpa, Wpa0, 3, h2a0, NAn, 128, 1);

  // ---- GNN2 layer 1 only needed at one paper row -> fused with classifier ----
  final_kernel<<<1, 128, 0, stream>>>(h2p0, h2a0, idxPtr,
                                      src_pp, w_pp_out, rowptr + RP_PPD, entries + EN_PPD,
                                      src_ap, rowptr + RP_APD, entries + EN_APD,
                                      Wself_p1, Wpp1, Wap1, Wc, bc, out);
}

// Round 2
// 491.493 us; speedup vs baseline: 1.5626x; 1.5626x over previous
//
#include <hip/hip_runtime.h>
#include <stdint.h>

// ---------------------------------------------------------------------------
// MultiGraph hetero-GNN + gumbel-top-k edge pruning, fp32 throughout.
// Round 2: edge_pred fused into row_topk (P1 cached per row), w==0 skip in
// weighted aggs, packed CSR payloads (src|e), batched agg + batched GEMM.
// PRNG: JAX threefry2x32, partitionable path (verified absmax=0.0 round 1).
// ---------------------------------------------------------------------------

namespace {

constexpr int NPn = 4096;
constexpr int NAn = 2048;
constexpr int Hh  = 128;
constexpr int EPPc = 131072;
constexpr int EAAc = 65536;
constexpr int EPAc = 131072;
constexpr int EAPc = 131072;
constexpr int KSEL = 5;

// CSR segments: 0 pp-dst, 1 aa-dst, 2 pa-dst, 3 ap-dst, 4 pp-src, 5 aa-src
// cnt offsets:    0(4096) 4096(2048) 6144(2048) 8192(4096) 12288(4096) 16384(2048)
// rowptr offsets: 0, 4097, 6146, 8195, 12292, 16389 (each N+1)
// entry offsets:  0, 131072, 196608, 327680, 458752, 589824 (total 655360)
// payloads: pp: (other<<18)|e  aa: (other<<16)|e  pa/ap: src only

__host__ __device__ static inline void tf2x32(uint32_t k0, uint32_t k1,
                                              uint32_t& x0, uint32_t& x1) {
  uint32_t ks2 = k0 ^ k1 ^ 0x1BD11BDAu;
  x0 += k0; x1 += k1;
#define TF_R(r) { x0 += x1; x1 = (x1 << (r)) | (x1 >> (32 - (r))); x1 ^= x0; }
  TF_R(13) TF_R(15) TF_R(26) TF_R(6)
  x0 += k1;  x1 += ks2 + 1u;
  TF_R(17) TF_R(29) TF_R(16) TF_R(24)
  x0 += ks2; x1 += k0 + 2u;
  TF_R(13) TF_R(15) TF_R(26) TF_R(6)
  x0 += k0;  x1 += k1 + 3u;
  TF_R(17) TF_R(29) TF_R(16) TF_R(24)
  x0 += k1;  x1 += ks2 + 4u;
  TF_R(13) TF_R(15) TF_R(26) TF_R(6)
  x0 += ks2; x1 += k0 + 5u;
#undef TF_R
}

// ---------------- CSR build ----------------
__global__ __launch_bounds__(256) void hist_kernel(
    const int* d0, const int* d1, const int* d2, const int* d3,
    const int* d4, const int* d5, int* cnt)
{
  int i = blockIdx.x * 256 + threadIdx.x;
  const int* kp; int co, e;
  if      (i < 131072) { kp = d0; co = 0;     e = i; }
  else if (i < 196608) { kp = d1; co = 4096;  e = i - 131072; }
  else if (i < 327680) { kp = d2; co = 6144;  e = i - 196608; }
  else if (i < 458752) { kp = d3; co = 8192;  e = i - 327680; }
  else if (i < 589824) { kp = d4; co = 12288; e = i - 458752; }
  else if (i < 655360) { kp = d5; co = 16384; e = i - 589824; }
  else return;
  atomicAdd(&cnt[co + kp[e]], 1);
}

__global__ __launch_bounds__(1024) void scan_kernel(const int* cnt, int* rowptr, int* cursor)
{
  __shared__ int buf[1024];
  const int Ns[6]   = {4096, 2048, 2048, 4096, 4096, 2048};
  const int coff[6] = {0, 4096, 6144, 8192, 12288, 16384};
  const int roff[6] = {0, 4097, 6146, 8195, 12292, 16389};
  int rel = blockIdx.x, tid = threadIdx.x;
  int N = Ns[rel], co = coff[rel], ro = roff[rel];
  int carry = 0;
  for (int base = 0; base < N; base += 1024) {
    int v = cnt[co + base + tid];
    buf[tid] = v; __syncthreads();
    for (int s = 1; s < 1024; s <<= 1) {
      int t = (tid >= s) ? buf[tid - s] : 0;
      __syncthreads();
      buf[tid] += t;
      __syncthreads();
    }
    int excl = carry + buf[tid] - v;
    rowptr[ro + base + tid] = excl;
    cursor[co + base + tid] = excl;
    carry += buf[1023];
    __syncthreads();
  }
  if (tid == 0) rowptr[ro + N] = carry;
}

__global__ __launch_bounds__(256) void scatter_kernel(
    const int* src_pp, const int* dst_pp, const int* src_aa, const int* dst_aa,
    const int* src_pa, const int* dst_pa, const int* src_ap, const int* dst_ap,
    int* cursor, int* entries)
{
  int i = blockIdx.x * 256 + threadIdx.x;
  int key, pl, co, eo;
  if (i < 131072) {                       // pp by dst
    int e = i;
    key = dst_pp[e]; pl = (src_pp[e] << 18) | e; co = 0; eo = 0;
  } else if (i < 196608) {                // aa by dst
    int e = i - 131072;
    key = dst_aa[e]; pl = (src_aa[e] << 16) | e; co = 4096; eo = 131072;
  } else if (i < 327680) {                // pa by dst (payload = src paper)
    int e = i - 196608;
    key = dst_pa[e]; pl = src_pa[e]; co = 6144; eo = 196608;
  } else if (i < 458752) {                // ap by dst (payload = src author)
    int e = i - 327680;
    key = dst_ap[e]; pl = src_ap[e]; co = 8192; eo = 327680;
  } else if (i < 589824) {                // pp by src (payload = (dst<<18)|e)
    int e = i - 458752;
    key = src_pp[e]; pl = (dst_pp[e] << 18) | e; co = 12288; eo = 458752;
  } else if (i < 655360) {                // aa by src
    int e = i - 589824;
    key = src_aa[e]; pl = (dst_aa[e] << 16) | e; co = 16384; eo = 589824;
  } else return;
  int pos = atomicAdd(&cursor[co + key], 1);
  entries[eo + pos] = pl;
}

// ---------------- batched mean aggregation --------------------------------------------
// M[d] = sum_e(w_e * h[src_e]) / max(count_all, 1); w==0 edges skipped (w in {0,1}).
struct AggSeg { const float* h; const float* w; float* M; int rpOff; int enOff; int shift; };
struct AggArgs { AggSeg s[4]; int start[5]; int nseg; };

__global__ __launch_bounds__(256) void multi_agg(AggArgs a, const int* __restrict__ rowptr,
                                                 const int* __restrict__ entries)
{
  int g = blockIdx.x * 4 + (threadIdx.x >> 6);
  int lane = threadIdx.x & 63;
  if (g >= a.start[a.nseg]) return;
  int si = 0;
  while (si < a.nseg - 1 && g >= a.start[si + 1]) ++si;
  AggSeg sg = a.s[si];
  int node = g - a.start[si];
  const int* rp = rowptr + sg.rpOff;
  const int* ent = entries + sg.enOff;
  int b = rp[node], e = rp[node + 1];
  unsigned mask = (1u << sg.shift) - 1u;
  float ax = 0.f, ay = 0.f;
  for (int k = b; k < e; ++k) {
    unsigned pl = (unsigned)ent[k];
    int s = (int)(pl >> sg.shift);
    float wt = 1.0f;
    if (sg.w) {
      wt = sg.w[pl & mask];
      if (wt == 0.f) continue;           // wave-uniform skip (hard 0/1 attention)
    }
    float2 v = *(const float2*)&sg.h[(size_t)s * Hh + lane * 2];
    ax += wt * v.x; ay += wt * v.y;
  }
  float cd = fmaxf((float)(e - b), 1.0f);
  float2 o; o.x = ax / cd; o.y = ay / cd;
  *(float2*)&sg.M[(size_t)node * Hh + lane * 2] = o;
}

// ---------------- batched multi-part fp32 GEMM: C = act(sum_p A_p[M,128] @ W_p[128,N]) --
struct GDesc {
  const float* A0; const float* W0; const float* A1; const float* W1;
  const float* A2; const float* W2; float* C; int M; int N; int parts; int relu;
};
struct GArgs { GDesc d[4]; int bstart[5]; int nd; };

__global__ __launch_bounds__(256) void gemm_b(GArgs g)
{
  __shared__ __align__(16) float As[32][68];  // [k][m]
  __shared__ __align__(16) float Ws[32][68];  // [k][n]
  int blk = blockIdx.x;
  int di = 0;
  while (di < g.nd - 1 && blk >= g.bstart[di + 1]) ++di;
  GDesc D = g.d[di];
  int local = blk - g.bstart[di];
  int nTiles = D.N >> 6;
  int bx = local % nTiles;
  int by = local / nTiles;
  int m0 = by << 6, n0 = bx << 6;
  int N = D.N;
  int tid = threadIdx.x;
  int tr = tid >> 4, tc = tid & 15;
  int r = tid >> 3, f = tid & 7;
  float acc[4][4] = {{0.f}};
  const float* Ap[3] = {D.A0, D.A1, D.A2};
  const float* Wp[3] = {D.W0, D.W1, D.W2};
  for (int pi = 0; pi < D.parts; ++pi) {
    const float* A = Ap[pi]; const float* W = Wp[pi];
    for (int k0 = 0; k0 < 128; k0 += 32) {
      float4 va0 = *(const float4*)&A[(size_t)(m0 + r) * 128 + k0 + f * 4];
      float4 va1 = *(const float4*)&A[(size_t)(m0 + r + 32) * 128 + k0 + f * 4];
      float4 vw0 = *(const float4*)&W[(size_t)(k0 + r) * N + n0 + f * 4];
      float4 vw1 = *(const float4*)&W[(size_t)(k0 + r) * N + n0 + f * 4 + 32];
      __syncthreads();
      As[f * 4 + 0][r] = va0.x; As[f * 4 + 1][r] = va0.y;
      As[f * 4 + 2][r] = va0.z; As[f * 4 + 3][r] = va0.w;
      As[f * 4 + 0][r + 32] = va1.x; As[f * 4 + 1][r + 32] = va1.y;
      As[f * 4 + 2][r + 32] = va1.z; As[f * 4 + 3][r + 32] = va1.w;
      *(float4*)&Ws[r][f * 4] = vw0;
      *(float4*)&Ws[r][f * 4 + 32] = vw1;
      __syncthreads();
#pragma unroll
      for (int k = 0; k < 32; ++k) {
        float4 a = *(const float4*)&As[k][tr * 4];
        float4 b = *(const float4*)&Ws[k][tc * 4];
        acc[0][0] += a.x * b.x; acc[0][1] += a.x * b.y; acc[0][2] += a.x * b.z; acc[0][3] += a.x * b.w;
        acc[1][0] += a.y * b.x; acc[1][1] += a.y * b.y; acc[1][2] += a.y * b.z; acc[1][3] += a.y * b.w;
        acc[2][0] += a.z * b.x; acc[2][1] += a.z * b.y; acc[2][2] += a.z * b.z; acc[2][3] += a.z * b.w;
        acc[3][0] += a.w * b.x; acc[3][1] += a.w * b.y; acc[3][2] += a.w * b.z; acc[3][3] += a.w * b.w;
      }
    }
  }
#pragma unroll
  for (int i = 0; i < 4; ++i) {
    float4 v;
    v.x = acc[i][0]; v.y = acc[i][1]; v.z = acc[i][2]; v.w = acc[i][3];
    if (D.relu) {
      v.x = fmaxf(v.x, 0.f); v.y = fmaxf(v.y, 0.f);
      v.z = fmaxf(v.z, 0.f); v.w = fmaxf(v.w, 0.f);
    }
    *(float4*)&D.C[(size_t)(m0 + tr * 4 + i) * N + n0 + tc * 4] = v;
  }
}

// ---------------- fused edge-MLP + coalesce + masked gumbel top-5 + w write -------------
// One block per src row. pred[e] = relu(P1[s]+P2[d]+b1).Wep2[:,0] + b2[0], scatter-added
// into ys[dst] (duplicate coalescing), then masked gumbel noise, 5 argmax passes,
// then w[e] = dst in sel5 ? 1 : 0.
__global__ __launch_bounds__(256) void row_topk(
    const float* __restrict__ P1pp, const float* __restrict__ P2pp,
    const float* __restrict__ b1pp, const float* __restrict__ W2pp,
    const float* __restrict__ b2pp,
    const float* __restrict__ P1aa, const float* __restrict__ P2aa,
    const float* __restrict__ b1aa, const float* __restrict__ W2aa,
    const float* __restrict__ b2aa,
    const int* __restrict__ rowptr, const int* __restrict__ entries,
    float* __restrict__ w_pp, float* __restrict__ w_aa,
    uint32_t kpp0, uint32_t kpp1, uint32_t kaa0, uint32_t kaa1)
{
  __shared__ float ys[4096];
  __shared__ float P1s[256], b1s[256], w2s[256];
  __shared__ float redv[256];
  __shared__ int   redc[256];
  __shared__ int   sel5[KSEL];
  int blk = blockIdx.x, tid = threadIdx.x;
  int lane = tid & 63, wv = tid >> 6;
  int row, Ncols, shift; unsigned mask;
  const float* P1; const float* P2; const float* b1; const float* W2; const float* b2;
  const int* rp; const int* ent; float* wout; uint32_t k0, k1;
  if (blk < NPn) {
    row = blk; Ncols = NPn; shift = 18; mask = 0x3FFFFu;
    P1 = P1pp; P2 = P2pp; b1 = b1pp; W2 = W2pp; b2 = b2pp;
    rp = rowptr + 12292; ent = entries + 458752;
    wout = w_pp; k0 = kpp0; k1 = kpp1;
  } else {
    row = blk - NPn; Ncols = NAn; shift = 16; mask = 0xFFFFu;
    P1 = P1aa; P2 = P2aa; b1 = b1aa; W2 = W2aa; b2 = b2aa;
    rp = rowptr + 16389; ent = entries + 589824;
    wout = w_aa; k0 = kaa0; k1 = kaa1;
  }
  P1s[tid] = P1[(size_t)row * 256 + tid];
  b1s[tid] = b1[tid];
  w2s[tid] = W2[tid * 2];
  for (int c = tid; c < Ncols; c += 256) ys[c] = 0.f;
  __syncthreads();
  float bias2 = b2[0];
  int beg = rp[row], end = rp[row + 1];
  // --- fused edge predictor: one wave per edge ---
  for (int k = beg + wv; k < end; k += 4) {
    unsigned pl = (unsigned)ent[k];
    int d = (int)(pl >> shift);
    float4 p2 = *(const float4*)&P2[(size_t)d * 256 + lane * 4];
    int j = lane * 4;
    float t0 = fmaxf(P1s[j + 0] + p2.x + b1s[j + 0], 0.f);
    float t1 = fmaxf(P1s[j + 1] + p2.y + b1s[j + 1], 0.f);
    float t2 = fmaxf(P1s[j + 2] + p2.z + b1s[j + 2], 0.f);
    float t3 = fmaxf(P1s[j + 3] + p2.w + b1s[j + 3], 0.f);
    float sum = t0 * w2s[j + 0] + t1 * w2s[j + 1] + t2 * w2s[j + 2] + t3 * w2s[j + 3];
    for (int off = 32; off; off >>= 1) sum += __shfl_down(sum, off);
    if (lane == 0) atomicAdd(&ys[d], sum + bias2);
  }
  __syncthreads();
  // --- masked gumbel noise at A>0 cells (threefry partitionable path) ---
  uint32_t rowbase = (uint32_t)row * (uint32_t)Ncols;
  for (int c = tid; c < Ncols; c += 256) {
    float a = ys[c];
    float y = -1e9f;
    if (a > 0.f) {
      uint32_t x0 = 0u, x1 = rowbase + (uint32_t)c;
      tf2x32(k0, k1, x0, x1);
      uint32_t bits = x0 ^ x1;
      float fl = __uint_as_float((bits >> 9) | 0x3f800000u) - 1.0f;
      float u = fmaxf(1e-10f, fl + 1e-10f);
      float g = -logf(-logf(u));
      y = a + g;  // tau == 1.0
    }
    ys[c] = y;
  }
  __syncthreads();
  // --- 5 exact argmax passes (lowest-index tie-break, matches lax.top_k) ---
  for (int it = 0; it < KSEL; ++it) {
    float best = -3.4e38f; int bcol = 0x7fffffff;
    for (int c = tid; c < Ncols; c += 256) {
      float v = ys[c];
      if (v > best) { best = v; bcol = c; }
    }
    redv[tid] = best; redc[tid] = bcol;
    __syncthreads();
    for (int s = 128; s; s >>= 1) {
      if (tid < s) {
        float v2 = redv[tid + s]; int c2 = redc[tid + s];
        if (v2 > redv[tid] || (v2 == redv[tid] && c2 < redc[tid])) {
          redv[tid] = v2; redc[tid] = c2;
        }
      }
      __syncthreads();
    }
    if (tid == 0) {
      sel5[it] = redc[0];
      ys[redc[0]] = -3.0e38f;  // below masked sentinel: never re-picked
    }
    __syncthreads();
  }
  // --- write hard 0/1 weights onto this row's edges ---
  for (int k = beg + tid; k < end; k += 256) {
    unsigned pl = (unsigned)ent[k];
    int d = (int)(pl >> shift);
    int e = (int)(pl & mask);
    float v = 0.f;
#pragma unroll
    for (int q = 0; q < KSEL; ++q) v = (sel5[q] == d) ? 1.f : v;
    wout[e] = v;
  }
}

// ---------------- fused GNN2-layer1 (single row) + classifier ---------------------------
__global__ __launch_bounds__(128) void final_kernel(
    const float* __restrict__ hp, const float* __restrict__ ha,
    const int* __restrict__ idxPtr, const float* __restrict__ wpp,
    const int* __restrict__ rp_ppd, const int* __restrict__ ent_ppd,
    const int* __restrict__ rp_apd, const int* __restrict__ ent_apd,
    const float* __restrict__ Wself, const float* __restrict__ Wpp,
    const float* __restrict__ Wap,
    const float* __restrict__ Wc, const float* __restrict__ bc,
    float* __restrict__ out)
{
  __shared__ float selfr[128], mpp[128], mapr[128], t[128];
  int tid = threadIdx.x;
  int idx = idxPtr[0];
  selfr[tid] = hp[(size_t)idx * 128 + tid];
  {
    int b = rp_ppd[idx], e2 = rp_ppd[idx + 1];
    float acc = 0.f;
    for (int k = b; k < e2; ++k) {
      unsigned pl = (unsigned)ent_ppd[k];
      int s = (int)(pl >> 18);
      int e = (int)(pl & 0x3FFFFu);
      acc += wpp[e] * hp[(size_t)s * 128 + tid];
    }
    mpp[tid] = acc / fmaxf((float)(e2 - b), 1.0f);
  }
  {
    int b = rp_apd[idx], e2 = rp_apd[idx + 1];
    float acc = 0.f;
    for (int k = b; k < e2; ++k) {
      int s = ent_apd[k];
      acc += ha[(size_t)s * 128 + tid];
    }
    mapr[tid] = acc / fmaxf((float)(e2 - b), 1.0f);
  }
  __syncthreads();
  float s = 0.f;
  for (int m = 0; m < 128; ++m) {
    s += selfr[m] * Wself[m * 128 + tid] + mpp[m] * Wpp[m * 128 + tid] +
         mapr[m] * Wap[m * 128 + tid];
  }
  t[tid] = fmaxf(s, 0.f);
  __syncthreads();
  if (tid < 5) {
    float y = bc[tid];
    for (int k = 0; k < 128; ++k) y += t[k] * Wc[k * 5 + tid];
    out[tid] = y;
  }
}

}  // namespace

extern "C" void kernel_launch(void* const* d_in, const int* in_sizes, int n_in,
                              void* d_out, int out_size, void* d_ws, size_t ws_size,
                              hipStream_t stream)
{
  (void)in_sizes; (void)n_in; (void)out_size; (void)ws_size;
  const float* x_p = (const float*)d_in[0];
  const float* x_a = (const float*)d_in[1];
  const int* ei_pp = (const int*)d_in[2];
  const int* ei_aa = (const int*)d_in[3];
  const int* ei_pa = (const int*)d_in[4];
  const int* ei_ap = (const int*)d_in[5];
  const int* idxPtr = (const int*)d_in[8];
  const float* Wself_p0 = (const float*)d_in[9];
  const float* Wself_p1 = (const float*)d_in[10];
  const float* Wself_a0 = (const float*)d_in[11];
  const float* Wself_a1 = (const float*)d_in[12];
  const float* Wpp0 = (const float*)d_in[13]; const float* Wpp1 = (const float*)d_in[14];
  const float* Waa0 = (const float*)d_in[15]; const float* Waa1 = (const float*)d_in[16];
  const float* Wpa0 = (const float*)d_in[17]; /* Wpa1 unused: author L1 dropped */
  const float* Wap0 = (const float*)d_in[19]; const float* Wap1 = (const float*)d_in[20];
  const float* Wep1_pp = (const float*)d_in[21]; const float* bep1_pp = (const float*)d_in[22];
  const float* Wep2_pp = (const float*)d_in[23]; const float* bep2_pp = (const float*)d_in[24];
  const float* Wep1_aa = (const float*)d_in[25]; const float* bep1_aa = (const float*)d_in[26];
  const float* Wep2_aa = (const float*)d_in[27]; const float* bep2_aa = (const float*)d_in[28];
  const float* Wc = (const float*)d_in[29]; const float* bc = (const float*)d_in[30];

  float* out = (float*)d_out;
  float* w_pp_out = out + 5;
  float* w_aa_out = out + 5 + EPPc;

  const int* src_pp = ei_pp;  const int* dst_pp = ei_pp + EPPc;
  const int* src_aa = ei_aa;  const int* dst_aa = ei_aa + EAAc;
  const int* src_pa = ei_pa;  const int* dst_pa = ei_pa + EPAc;
  const int* src_ap = ei_ap;  const int* dst_ap = ei_ap + EAPc;

  // ---- workspace layout (bump allocator; cnt first: it gets memset) ----
  char* p = (char*)d_ws;
  auto alloc = [&](size_t bytes) -> void* {
    void* r = (void*)p;
    p += (bytes + 255) & ~(size_t)255;
    return r;
  };
  int* cnt     = (int*)alloc(18432 * sizeof(int));
  int* rowptr  = (int*)alloc(18438 * sizeof(int));
  int* cursor  = (int*)alloc(18432 * sizeof(int));
  int* entries = (int*)alloc(655360 * sizeof(int));
  float* Mpp  = (float*)alloc((size_t)NPn * Hh * sizeof(float));
  float* Maa  = (float*)alloc((size_t)NAn * Hh * sizeof(float));
  float* Mpa  = (float*)alloc((size_t)NAn * Hh * sizeof(float));
  float* Map  = (float*)alloc((size_t)NPn * Hh * sizeof(float));
  float* h1p0 = (float*)alloc((size_t)NPn * Hh * sizeof(float));
  float* h1a0 = (float*)alloc((size_t)NAn * Hh * sizeof(float));
  float* h1p1 = (float*)alloc((size_t)NPn * Hh * sizeof(float));
  float* h1a1 = (float*)alloc((size_t)NAn * Hh * sizeof(float));
  float* h2p0 = (float*)alloc((size_t)NPn * Hh * sizeof(float));
  float* h2a0 = (float*)alloc((size_t)NAn * Hh * sizeof(float));
  float* P1pp = (float*)alloc((size_t)NPn * 256 * sizeof(float));
  float* P2pp = (float*)alloc((size_t)NPn * 256 * sizeof(float));
  float* P1aa = (float*)alloc((size_t)NAn * 256 * sizeof(float));
  float* P2aa = (float*)alloc((size_t)NAn * 256 * sizeof(float));

  const int RP_PPD = 0, RP_AAD = 4097, RP_PAD = 6146, RP_APD = 8195;
  const int EN_PPD = 0, EN_AAD = 131072, EN_PAD = 196608, EN_APD = 327680;

  hipMemsetAsync(cnt, 0, 18432 * sizeof(int), stream);
  hist_kernel<<<2560, 256, 0, stream>>>(dst_pp, dst_aa, dst_pa, dst_ap, src_pp, src_aa, cnt);
  scan_kernel<<<6, 1024, 0, stream>>>(cnt, rowptr, cursor);
  scatter_kernel<<<2560, 256, 0, stream>>>(src_pp, dst_pp, src_aa, dst_aa,
                                           src_pa, dst_pa, src_ap, dst_ap,
                                           cursor, entries);

  // ---- GNN1 (single=True: pp, aa only) ----
  {
    AggArgs a{};
    a.s[0] = {x_p, nullptr, Mpp, RP_PPD, EN_PPD, 18};
    a.s[1] = {x_a, nullptr, Maa, RP_AAD, EN_AAD, 16};
    a.start[0] = 0; a.start[1] = NPn; a.start[2] = NPn + NAn; a.nseg = 2;
    multi_agg<<<(NPn + NAn) / 4, 256, 0, stream>>>(a, rowptr, entries);
  }
  {
    GArgs g{};
    g.d[0] = {x_p, Wself_p0, Mpp, Wpp0, nullptr, nullptr, h1p0, NPn, 128, 2, 1};
    g.d[1] = {x_a, Wself_a0, Maa, Waa0, nullptr, nullptr, h1a0, NAn, 128, 2, 1};
    g.bstart[0] = 0; g.bstart[1] = 128; g.bstart[2] = 192; g.nd = 2;
    gemm_b<<<192, 256, 0, stream>>>(g);
  }
  {
    AggArgs a{};
    a.s[0] = {h1p0, nullptr, Mpp, RP_PPD, EN_PPD, 18};
    a.s[1] = {h1a0, nullptr, Maa, RP_AAD, EN_AAD, 16};
    a.start[0] = 0; a.start[1] = NPn; a.start[2] = NPn + NAn; a.nseg = 2;
    multi_agg<<<(NPn + NAn) / 4, 256, 0, stream>>>(a, rowptr, entries);
  }
  {
    GArgs g{};
    g.d[0] = {h1p0, Wself_p1, Mpp, Wpp1, nullptr, nullptr, h1p1, NPn, 128, 2, 1};
    g.d[1] = {h1a0, Wself_a1, Maa, Waa1, nullptr, nullptr, h1a1, NAn, 128, 2, 1};
    g.bstart[0] = 0; g.bstart[1] = 128; g.bstart[2] = 192; g.nd = 2;
    gemm_b<<<192, 256, 0, stream>>>(g);
  }

  // ---- edge MLP node projections: concat(h_s,h_d)@Wep1 == P1[s] + P2[d] ----
  {
    GArgs g{};
    g.d[0] = {h1p1, Wep1_pp,             nullptr, nullptr, nullptr, nullptr, P1pp, NPn, 256, 1, 0};
    g.d[1] = {h1p1, Wep1_pp + 128 * 256, nullptr, nullptr, nullptr, nullptr, P2pp, NPn, 256, 1, 0};
    g.d[2] = {h1a1, Wep1_aa,             nullptr, nullptr, nullptr, nullptr, P1aa, NAn, 256, 1, 0};
    g.d[3] = {h1a1, Wep1_aa + 128 * 256, nullptr, nullptr, nullptr, nullptr, P2aa, NAn, 256, 1, 0};
    g.bstart[0] = 0; g.bstart[1] = 256; g.bstart[2] = 512; g.bstart[3] = 640;
    g.bstart[4] = 768; g.nd = 4;
    gemm_b<<<768, 256, 0, stream>>>(g);
  }

  // ---- JAX keys: key(42) -> split -> (kpp, kaa) (partitionable fold-in) ----
  uint32_t kpp0, kpp1, kaa0, kaa1;
  { uint32_t a0 = 0, a1 = 0; tf2x32(0u, 42u, a0, a1); kpp0 = a0; kpp1 = a1; }
  { uint32_t a0 = 0, a1 = 1; tf2x32(0u, 42u, a0, a1); kaa0 = a0; kaa1 = a1; }

  // ---- fused edge-pred + coalesce + gumbel top-5 + w write ----
  row_topk<<<NPn + NAn, 256, 0, stream>>>(P1pp, P2pp, bep1_pp, Wep2_pp, bep2_pp,
                                          P1aa, P2aa, bep1_aa, Wep2_aa, bep2_aa,
                                          rowptr, entries, w_pp_out, w_aa_out,
                                          kpp0, kpp1, kaa0, kaa1);

  // ---- GNN2 layer 0 (all relations; pp/aa with hard attention weights, w==0 skipped) ----
  {
    AggArgs a{};
    a.s[0] = {x_p, w_pp_out, Mpp, RP_PPD, EN_PPD, 18};
    a.s[1] = {x_a, nullptr,  Map, RP_APD, EN_APD, 0};
    a.s[2] = {x_a, w_aa_out, Maa, RP_AAD, EN_AAD, 16};
    a.s[3] = {x_p, nullptr,  Mpa, RP_PAD, EN_PAD, 0};
    a.start[0] = 0; a.start[1] = NPn; a.start[2] = 2 * NPn;
    a.start[3] = 2 * NPn + NAn; a.start[4] = 2 * NPn + 2 * NAn; a.nseg = 4;
    multi_agg<<<(2 * NPn + 2 * NAn) / 4, 256, 0, stream>>>(a, rowptr, entries);
  }
  {
    GArgs g{};
    g.d[0] = {x_p, Wself_p0, Mpp, Wpp0, Map, Wap0, h2p0, NPn, 128, 3, 1};
    g.d[1] = {x_a, Wself_a0, Maa, Waa0, Mpa, Wpa0, h2a0, NAn, 128, 3, 1};
    g.bstart[0] = 0; g.bstart[1] = 128; g.bstart[2] = 192; g.nd = 2;
    gemm_b<<<192, 256, 0, stream>>>(g);
  }

  // ---- GNN2 layer 1 only needed at one paper row -> fused with classifier ----
  final_kernel<<<1, 128, 0, stream>>>(h2p0, h2a0, idxPtr, w_pp_out,
                                      rowptr + RP_PPD, entries + EN_PPD,
                                      rowptr + RP_APD, entries + EN_APD,
                                      Wself_p1, Wpp1, Wap1, Wc, bc, out);
}

// Round 3
// 418.824 us; speedup vs baseline: 1.8337x; 1.1735x over previous
//
#include <hip/hip_runtime.h>
#include <stdint.h>

// ---------------------------------------------------------------------------
// MultiGraph hetero-GNN + gumbel-top-k edge pruning, fp32 throughout.
// Round 3: candidate-compacted top-5 (no block barriers in common path),
// 2-edge ILP in fused edge-pred, multi_agg with 2 nodes/wave + float4 lanes
// (per-node sequential order preserved), single-barrier scan.
// PRNG: JAX threefry2x32, partitionable path (verified absmax=0.0 r1/r2).
// ---------------------------------------------------------------------------

namespace {

constexpr int NPn = 4096;
constexpr int NAn = 2048;
constexpr int Hh  = 128;
constexpr int EPPc = 131072;
constexpr int EAAc = 65536;
constexpr int EPAc = 131072;
constexpr int EAPc = 131072;
constexpr int KSEL = 5;

// CSR segments: 0 pp-dst, 1 aa-dst, 2 pa-dst, 3 ap-dst, 4 pp-src, 5 aa-src
// cnt offsets:    0(4096) 4096(2048) 6144(2048) 8192(4096) 12288(4096) 16384(2048)
// rowptr offsets: 0, 4097, 6146, 8195, 12292, 16389 (each N+1)
// entry offsets:  0, 131072, 196608, 327680, 458752, 589824 (total 655360)
// payloads: pp: (other<<18)|e  aa: (other<<16)|e  pa/ap: src only

__host__ __device__ static inline void tf2x32(uint32_t k0, uint32_t k1,
                                              uint32_t& x0, uint32_t& x1) {
  uint32_t ks2 = k0 ^ k1 ^ 0x1BD11BDAu;
  x0 += k0; x1 += k1;
#define TF_R(r) { x0 += x1; x1 = (x1 << (r)) | (x1 >> (32 - (r))); x1 ^= x0; }
  TF_R(13) TF_R(15) TF_R(26) TF_R(6)
  x0 += k1;  x1 += ks2 + 1u;
  TF_R(17) TF_R(29) TF_R(16) TF_R(24)
  x0 += ks2; x1 += k0 + 2u;
  TF_R(13) TF_R(15) TF_R(26) TF_R(6)
  x0 += k0;  x1 += k1 + 3u;
  TF_R(17) TF_R(29) TF_R(16) TF_R(24)
  x0 += k1;  x1 += ks2 + 4u;
  TF_R(13) TF_R(15) TF_R(26) TF_R(6)
  x0 += ks2; x1 += k0 + 5u;
#undef TF_R
}

// ---------------- CSR build ----------------
__global__ __launch_bounds__(256) void hist_kernel(
    const int* d0, const int* d1, const int* d2, const int* d3,
    const int* d4, const int* d5, int* cnt)
{
  int i = blockIdx.x * 256 + threadIdx.x;
  const int* kp; int co, e;
  if      (i < 131072) { kp = d0; co = 0;     e = i; }
  else if (i < 196608) { kp = d1; co = 4096;  e = i - 131072; }
  else if (i < 327680) { kp = d2; co = 6144;  e = i - 196608; }
  else if (i < 458752) { kp = d3; co = 8192;  e = i - 327680; }
  else if (i < 589824) { kp = d4; co = 12288; e = i - 458752; }
  else if (i < 655360) { kp = d5; co = 16384; e = i - 589824; }
  else return;
  atomicAdd(&cnt[co + kp[e]], 1);
}

// One 256-thread block per relation; shfl-based scan, single barrier.
__global__ __launch_bounds__(256) void scan_kernel(const int* cnt, int* rowptr, int* cursor)
{
  __shared__ int wsum[4];
  const int Ns[6]   = {4096, 2048, 2048, 4096, 4096, 2048};
  const int coff[6] = {0, 4096, 6144, 8192, 12288, 16384};
  const int roff[6] = {0, 4097, 6146, 8195, 12292, 16389};
  int rel = blockIdx.x, tid = threadIdx.x;
  int N = Ns[rel], co = coff[rel], ro = roff[rel];
  int per = N >> 8;                 // 16 or 8
  int base = tid * per;
  int local[16];
  int s = 0;
  for (int i = 0; i < per; ++i) { local[i] = s; s += cnt[co + base + i]; }
  int lane = tid & 63, wv = tid >> 6;
  int x = s;
  for (int d = 1; d < 64; d <<= 1) {
    int y = __shfl_up(x, d);
    if (lane >= d) x += y;
  }
  if (lane == 63) wsum[wv] = x;
  __syncthreads();
  int woff = 0;
  for (int q = 0; q < wv; ++q) woff += wsum[q];
  int excl = woff + x - s;
  for (int i = 0; i < per; ++i) {
    int v = excl + local[i];
    rowptr[ro + base + i] = v;
    cursor[co + base + i] = v;
  }
  if (tid == 255) rowptr[ro + N] = excl + s;
}

__global__ __launch_bounds__(256) void scatter_kernel(
    const int* src_pp, const int* dst_pp, const int* src_aa, const int* dst_aa,
    const int* src_pa, const int* dst_pa, const int* src_ap, const int* dst_ap,
    int* cursor, int* entries)
{
  int i = blockIdx.x * 256 + threadIdx.x;
  int key, pl, co, eo;
  if (i < 131072) {                       // pp by dst
    int e = i;
    key = dst_pp[e]; pl = (src_pp[e] << 18) | e; co = 0; eo = 0;
  } else if (i < 196608) {                // aa by dst
    int e = i - 131072;
    key = dst_aa[e]; pl = (src_aa[e] << 16) | e; co = 4096; eo = 131072;
  } else if (i < 327680) {                // pa by dst (payload = src paper)
    int e = i - 196608;
    key = dst_pa[e]; pl = src_pa[e]; co = 6144; eo = 196608;
  } else if (i < 458752) {                // ap by dst (payload = src author)
    int e = i - 327680;
    key = dst_ap[e]; pl = src_ap[e]; co = 8192; eo = 327680;
  } else if (i < 589824) {                // pp by src (payload = (dst<<18)|e)
    int e = i - 458752;
    key = src_pp[e]; pl = (dst_pp[e] << 18) | e; co = 12288; eo = 458752;
  } else if (i < 655360) {                // aa by src
    int e = i - 589824;
    key = src_aa[e]; pl = (dst_aa[e] << 16) | e; co = 16384; eo = 589824;
  } else return;
  int pos = atomicAdd(&cursor[co + key], 1);
  entries[eo + pos] = pl;
}

// ---------------- batched mean aggregation --------------------------------------------
// 2 nodes per wave: half-wave (32 lanes) per node, lane covers 4 floats (float4).
// Per-node edge loop stays SEQUENTIAL in CSR order -> summation order identical to r2.
struct AggSeg { const float* h; const float* w; float* M; int rpOff; int enOff; int shift; };
struct AggArgs { AggSeg s[4]; int start[5]; int nseg; };

__global__ __launch_bounds__(256) void multi_agg(AggArgs a, const int* __restrict__ rowptr,
                                                 const int* __restrict__ entries)
{
  int g = blockIdx.x * 8 + (threadIdx.x >> 5);   // 8 half-waves = 8 nodes per block
  int fl = (threadIdx.x & 31) << 2;              // float4 feature offset
  if (g >= a.start[a.nseg]) return;
  int si = 0;
  while (si < a.nseg - 1 && g >= a.start[si + 1]) ++si;
  AggSeg sg = a.s[si];
  int node = g - a.start[si];
  const int* rp = rowptr + sg.rpOff;
  const int* ent = entries + sg.enOff;
  int b = rp[node], e = rp[node + 1];
  float ax = 0.f, ay = 0.f, az = 0.f, aw = 0.f;
  if (sg.w) {
    unsigned mask = (1u << sg.shift) - 1u;
    for (int k = b; k < e; ++k) {
      unsigned pl = (unsigned)ent[k];
      float wt = sg.w[pl & mask];
      if (wt != 0.f) {                 // w is exactly {0,1}: add selected rows
        int s = (int)(pl >> sg.shift);
        float4 v = *(const float4*)&sg.h[(size_t)s * Hh + fl];
        ax += v.x; ay += v.y; az += v.z; aw += v.w;
      }
    }
  } else {
#pragma unroll 2
    for (int k = b; k < e; ++k) {
      unsigned pl = (unsigned)ent[k];
      int s = (int)(pl >> sg.shift);
      float4 v = *(const float4*)&sg.h[(size_t)s * Hh + fl];
      ax += v.x; ay += v.y; az += v.z; aw += v.w;
    }
  }
  float cd = fmaxf((float)(e - b), 1.0f);
  float4 o; o.x = ax / cd; o.y = ay / cd; o.z = az / cd; o.w = aw / cd;
  *(float4*)&sg.M[(size_t)node * Hh + fl] = o;
}

// ---------------- batched multi-part fp32 GEMM: C = act(sum_p A_p[M,128] @ W_p[128,N]) --
struct GDesc {
  const float* A0; const float* W0; const float* A1; const float* W1;
  const float* A2; const float* W2; float* C; int M; int N; int parts; int relu;
};
struct GArgs { GDesc d[4]; int bstart[5]; int nd; };

__global__ __launch_bounds__(256) void gemm_b(GArgs g)
{
  __shared__ __align__(16) float As[32][68];  // [k][m]
  __shared__ __align__(16) float Ws[32][68];  // [k][n]
  int blk = blockIdx.x;
  int di = 0;
  while (di < g.nd - 1 && blk >= g.bstart[di + 1]) ++di;
  GDesc D = g.d[di];
  int local = blk - g.bstart[di];
  int nTiles = D.N >> 6;
  int bx = local % nTiles;
  int by = local / nTiles;
  int m0 = by << 6, n0 = bx << 6;
  int N = D.N;
  int tid = threadIdx.x;
  int tr = tid >> 4, tc = tid & 15;
  int r = tid >> 3, f = tid & 7;
  float acc[4][4] = {{0.f}};
  const float* Ap[3] = {D.A0, D.A1, D.A2};
  const float* Wp[3] = {D.W0, D.W1, D.W2};
  for (int pi = 0; pi < D.parts; ++pi) {
    const float* A = Ap[pi]; const float* W = Wp[pi];
    for (int k0 = 0; k0 < 128; k0 += 32) {
      float4 va0 = *(const float4*)&A[(size_t)(m0 + r) * 128 + k0 + f * 4];
      float4 va1 = *(const float4*)&A[(size_t)(m0 + r + 32) * 128 + k0 + f * 4];
      float4 vw0 = *(const float4*)&W[(size_t)(k0 + r) * N + n0 + f * 4];
      float4 vw1 = *(const float4*)&W[(size_t)(k0 + r) * N + n0 + f * 4 + 32];
      __syncthreads();
      As[f * 4 + 0][r] = va0.x; As[f * 4 + 1][r] = va0.y;
      As[f * 4 + 2][r] = va0.z; As[f * 4 + 3][r] = va0.w;
      As[f * 4 + 0][r + 32] = va1.x; As[f * 4 + 1][r + 32] = va1.y;
      As[f * 4 + 2][r + 32] = va1.z; As[f * 4 + 3][r + 32] = va1.w;
      *(float4*)&Ws[r][f * 4] = vw0;
      *(float4*)&Ws[r][f * 4 + 32] = vw1;
      __syncthreads();
#pragma unroll
      for (int k = 0; k < 32; ++k) {
        float4 a = *(const float4*)&As[k][tr * 4];
        float4 b = *(const float4*)&Ws[k][tc * 4];
        acc[0][0] += a.x * b.x; acc[0][1] += a.x * b.y; acc[0][2] += a.x * b.z; acc[0][3] += a.x * b.w;
        acc[1][0] += a.y * b.x; acc[1][1] += a.y * b.y; acc[1][2] += a.y * b.z; acc[1][3] += a.y * b.w;
        acc[2][0] += a.z * b.x; acc[2][1] += a.z * b.y; acc[2][2] += a.z * b.z; acc[2][3] += a.z * b.w;
        acc[3][0] += a.w * b.x; acc[3][1] += a.w * b.y; acc[3][2] += a.w * b.z; acc[3][3] += a.w * b.w;
      }
    }
  }
#pragma unroll
  for (int i = 0; i < 4; ++i) {
    float4 v;
    v.x = acc[i][0]; v.y = acc[i][1]; v.z = acc[i][2]; v.w = acc[i][3];
    if (D.relu) {
      v.x = fmaxf(v.x, 0.f); v.y = fmaxf(v.y, 0.f);
      v.z = fmaxf(v.z, 0.f); v.w = fmaxf(v.w, 0.f);
    }
    *(float4*)&D.C[(size_t)(m0 + tr * 4 + i) * N + n0 + tc * 4] = v;
  }
}

// ---------------- fused edge-MLP + coalesce + masked gumbel top-5 + w write -------------
// One block per src row. Edge pred scatter-added into ys[dst] (duplicate coalescing),
// then A>0 cells compacted with gumbel noise into a candidate list; wave 0 runs 5
// shuffle-reduce argmax passes (no block barriers). Dense fallback for rare rows.
__global__ __launch_bounds__(256) void row_topk(
    const float* __restrict__ P1pp, const float* __restrict__ P2pp,
    const float* __restrict__ b1pp, const float* __restrict__ W2pp,
    const float* __restrict__ b2pp,
    const float* __restrict__ P1aa, const float* __restrict__ P2aa,
    const float* __restrict__ b1aa, const float* __restrict__ W2aa,
    const float* __restrict__ b2aa,
    const int* __restrict__ rowptr, const int* __restrict__ entries,
    float* __restrict__ w_pp, float* __restrict__ w_aa,
    uint32_t kpp0, uint32_t kpp1, uint32_t kaa0, uint32_t kaa1)
{
  __shared__ float ys[4096];
  __shared__ float P1s[256], b1s[256], w2s[256];
  __shared__ float scrF[256];
  __shared__ int   scrI[256];
  __shared__ int   sel5[KSEL];
  __shared__ int   candCnt;
  int blk = blockIdx.x, tid = threadIdx.x;
  int lane = tid & 63, wv = tid >> 6;
  int row, Ncols, shift; unsigned mask;
  const float* P1; const float* P2; const float* b1; const float* W2; const float* b2;
  const int* rp; const int* ent; float* wout; uint32_t k0, k1;
  if (blk < NPn) {
    row = blk; Ncols = NPn; shift = 18; mask = 0x3FFFFu;
    P1 = P1pp; P2 = P2pp; b1 = b1pp; W2 = W2pp; b2 = b2pp;
    rp = rowptr + 12292; ent = entries + 458752;
    wout = w_pp; k0 = kpp0; k1 = kpp1;
  } else {
    row = blk - NPn; Ncols = NAn; shift = 16; mask = 0xFFFFu;
    P1 = P1aa; P2 = P2aa; b1 = b1aa; W2 = W2aa; b2 = b2aa;
    rp = rowptr + 16389; ent = entries + 589824;
    wout = w_aa; k0 = kaa0; k1 = kaa1;
  }
  P1s[tid] = P1[(size_t)row * 256 + tid];
  b1s[tid] = b1[tid];
  w2s[tid] = W2[tid * 2];
  if (tid == 0) candCnt = 0;
  for (int c = tid; c < Ncols; c += 256) ys[c] = 0.f;
  __syncthreads();
  float bias2 = b2[0];
  int beg = rp[row], end = rp[row + 1];
  // --- fused edge predictor: 2 edges per wave (independent gathers for ILP) ---
  for (int k = beg + wv * 2; k < end; k += 8) {
    int k1i = k + 1;
    bool has1 = (k1i < end);
    unsigned pl0 = (unsigned)ent[k];
    unsigned pl1 = has1 ? (unsigned)ent[k1i] : pl0;
    int d0 = (int)(pl0 >> shift);
    int d1 = (int)(pl1 >> shift);
    int j = lane << 2;
    float4 q0 = *(const float4*)&P2[(size_t)d0 * 256 + j];
    float4 q1 = *(const float4*)&P2[(size_t)d1 * 256 + j];
    float t00 = fmaxf(P1s[j + 0] + q0.x + b1s[j + 0], 0.f);
    float t01 = fmaxf(P1s[j + 1] + q0.y + b1s[j + 1], 0.f);
    float t02 = fmaxf(P1s[j + 2] + q0.z + b1s[j + 2], 0.f);
    float t03 = fmaxf(P1s[j + 3] + q0.w + b1s[j + 3], 0.f);
    float s0 = t00 * w2s[j + 0] + t01 * w2s[j + 1] + t02 * w2s[j + 2] + t03 * w2s[j + 3];
    float t10 = fmaxf(P1s[j + 0] + q1.x + b1s[j + 0], 0.f);
    float t11 = fmaxf(P1s[j + 1] + q1.y + b1s[j + 1], 0.f);
    float t12 = fmaxf(P1s[j + 2] + q1.z + b1s[j + 2], 0.f);
    float t13 = fmaxf(P1s[j + 3] + q1.w + b1s[j + 3], 0.f);
    float s1 = t10 * w2s[j + 0] + t11 * w2s[j + 1] + t12 * w2s[j + 2] + t13 * w2s[j + 3];
    for (int off = 32; off; off >>= 1) {
      s0 += __shfl_down(s0, off);
      s1 += __shfl_down(s1, off);
    }
    if (lane == 0) {
      atomicAdd(&ys[d0], s0 + bias2);
      if (has1) atomicAdd(&ys[d1], s1 + bias2);
    }
  }
  __syncthreads();
  // --- compact A>0 candidates with gumbel noise (threefry partitionable path) ---
  uint32_t rowbase = (uint32_t)row * (uint32_t)Ncols;
  for (int c = tid; c < Ncols; c += 256) {
    float a = ys[c];
    if (a > 0.f) {
      uint32_t x0 = 0u, x1 = rowbase + (uint32_t)c;
      tf2x32(k0, k1, x0, x1);
      uint32_t bits = x0 ^ x1;
      float fl = __uint_as_float((bits >> 9) | 0x3f800000u) - 1.0f;
      float u = fmaxf(1e-10f, fl + 1e-10f);
      float gn = -logf(-logf(u));
      float y = a + gn;  // tau == 1.0
      int pos = atomicAdd(&candCnt, 1);
      if (pos < 256) { scrF[pos] = y; scrI[pos] = c; }
    }
  }
  __syncthreads();
  int cnt = candCnt;   // block-uniform
  if (cnt >= KSEL && cnt <= 256) {
    // --- fast path: wave 0 selects top-5 from candidates (no block barriers) ---
    if (wv == 0) {
      int sreg[KSEL];
#pragma unroll
      for (int it = 0; it < KSEL; ++it) {
        float best = -3.4e38f; int bc = 0x7fffffff;
        for (int kk = lane; kk < cnt; kk += 64) {
          int c = scrI[kk];
          bool dead = false;
#pragma unroll
          for (int q = 0; q < KSEL; ++q) dead |= (q < it) && (c == sreg[q]);
          if (!dead) {
            float v = scrF[kk];
            if (v > best || (v == best && c < bc)) { best = v; bc = c; }
          }
        }
        for (int m = 32; m; m >>= 1) {
          float ov = __shfl_xor(best, m); int oc = __shfl_xor(bc, m);
          if (ov > best || (ov == best && oc < bc)) { best = ov; bc = oc; }
        }
        sreg[it] = bc;                    // all lanes agree post-reduce
        if (lane == 0) sel5[it] = bc;
      }
    }
  } else {
    // --- dense fallback (rare: <5 candidates or overflow); round-2-proven path ---
    for (int c = tid; c < Ncols; c += 256) {
      float a = ys[c];
      float y = -1e9f;
      if (a > 0.f) {
        uint32_t x0 = 0u, x1 = rowbase + (uint32_t)c;
        tf2x32(k0, k1, x0, x1);
        uint32_t bits = x0 ^ x1;
        float fl = __uint_as_float((bits >> 9) | 0x3f800000u) - 1.0f;
        float u = fmaxf(1e-10f, fl + 1e-10f);
        float gn = -logf(-logf(u));
        y = a + gn;
      }
      ys[c] = y;
    }
    __syncthreads();
    for (int it = 0; it < KSEL; ++it) {
      float best = -3.4e38f; int bcol = 0x7fffffff;
      for (int c = tid; c < Ncols; c += 256) {
        float v = ys[c];
        if (v > best) { best = v; bcol = c; }
      }
      scrF[tid] = best; scrI[tid] = bcol;
      __syncthreads();
      for (int s = 128; s; s >>= 1) {
        if (tid < s) {
          float v2 = scrF[tid + s]; int c2 = scrI[tid + s];
          if (v2 > scrF[tid] || (v2 == scrF[tid] && c2 < scrI[tid])) {
            scrF[tid] = v2; scrI[tid] = c2;
          }
        }
        __syncthreads();
      }
      if (tid == 0) {
        sel5[it] = scrI[0];
        ys[scrI[0]] = -3.0e38f;
      }
      __syncthreads();
    }
  }
  __syncthreads();
  // --- write hard 0/1 weights onto this row's edges ---
  for (int k = beg + tid; k < end; k += 256) {
    unsigned pl = (unsigned)ent[k];
    int d = (int)(pl >> shift);
    int e = (int)(pl & mask);
    float v = 0.f;
#pragma unroll
    for (int q = 0; q < KSEL; ++q) v = (sel5[q] == d) ? 1.f : v;
    wout[e] = v;
  }
}

// ---------------- fused GNN2-layer1 (single row) + classifier ---------------------------
__global__ __launch_bounds__(128) void final_kernel(
    const float* __restrict__ hp, const float* __restrict__ ha,
    const int* __restrict__ idxPtr, const float* __restrict__ wpp,
    const int* __restrict__ rp_ppd, const int* __restrict__ ent_ppd,
    const int* __restrict__ rp_apd, const int* __restrict__ ent_apd,
    const float* __restrict__ Wself, const float* __restrict__ Wpp,
    const float* __restrict__ Wap,
    const float* __restrict__ Wc, const float* __restrict__ bc,
    float* __restrict__ out)
{
  __shared__ float selfr[128], mpp[128], mapr[128], t[128];
  int tid = threadIdx.x;
  int idx = idxPtr[0];
  selfr[tid] = hp[(size_t)idx * 128 + tid];
  {
    int b = rp_ppd[idx], e2 = rp_ppd[idx + 1];
    float acc = 0.f;
    for (int k = b; k < e2; ++k) {
      unsigned pl = (unsigned)ent_ppd[k];
      int s = (int)(pl >> 18);
      int e = (int)(pl & 0x3FFFFu);
      acc += wpp[e] * hp[(size_t)s * 128 + tid];
    }
    mpp[tid] = acc / fmaxf((float)(e2 - b), 1.0f);
  }
  {
    int b = rp_apd[idx], e2 = rp_apd[idx + 1];
    float acc = 0.f;
    for (int k = b; k < e2; ++k) {
      int s = ent_apd[k];
      acc += ha[(size_t)s * 128 + tid];
    }
    mapr[tid] = acc / fmaxf((float)(e2 - b), 1.0f);
  }
  __syncthreads();
  float s = 0.f;
  for (int m = 0; m < 128; ++m) {
    s += selfr[m] * Wself[m * 128 + tid] + mpp[m] * Wpp[m * 128 + tid] +
         mapr[m] * Wap[m * 128 + tid];
  }
  t[tid] = fmaxf(s, 0.f);
  __syncthreads();
  if (tid < 5) {
    float y = bc[tid];
    for (int k = 0; k < 128; ++k) y += t[k] * Wc[k * 5 + tid];
    out[tid] = y;
  }
}

}  // namespace

extern "C" void kernel_launch(void* const* d_in, const int* in_sizes, int n_in,
                              void* d_out, int out_size, void* d_ws, size_t ws_size,
                              hipStream_t stream)
{
  (void)in_sizes; (void)n_in; (void)out_size; (void)ws_size;
  const float* x_p = (const float*)d_in[0];
  const float* x_a = (const float*)d_in[1];
  const int* ei_pp = (const int*)d_in[2];
  const int* ei_aa = (const int*)d_in[3];
  const int* ei_pa = (const int*)d_in[4];
  const int* ei_ap = (const int*)d_in[5];
  const int* idxPtr = (const int*)d_in[8];
  const float* Wself_p0 = (const float*)d_in[9];
  const float* Wself_p1 = (const float*)d_in[10];
  const float* Wself_a0 = (const float*)d_in[11];
  const float* Wself_a1 = (const float*)d_in[12];
  const float* Wpp0 = (const float*)d_in[13]; const float* Wpp1 = (const float*)d_in[14];
  const float* Waa0 = (const float*)d_in[15]; const float* Waa1 = (const float*)d_in[16];
  const float* Wpa0 = (const float*)d_in[17]; /* Wpa1 unused: author L1 dropped */
  const float* Wap0 = (const float*)d_in[19]; const float* Wap1 = (const float*)d_in[20];
  const float* Wep1_pp = (const float*)d_in[21]; const float* bep1_pp = (const float*)d_in[22];
  const float* Wep2_pp = (const float*)d_in[23]; const float* bep2_pp = (const float*)d_in[24];
  const float* Wep1_aa = (const float*)d_in[25]; const float* bep1_aa = (const float*)d_in[26];
  const float* Wep2_aa = (const float*)d_in[27]; const float* bep2_aa = (const float*)d_in[28];
  const float* Wc = (const float*)d_in[29]; const float* bc = (const float*)d_in[30];

  float* out = (float*)d_out;
  float* w_pp_out = out + 5;
  float* w_aa_out = out + 5 + EPPc;

  const int* src_pp = ei_pp;  const int* dst_pp = ei_pp + EPPc;
  const int* src_aa = ei_aa;  const int* dst_aa = ei_aa + EAAc;
  const int* src_pa = ei_pa;  const int* dst_pa = ei_pa + EPAc;
  const int* src_ap = ei_ap;  const int* dst_ap = ei_ap + EAPc;

  // ---- workspace layout (bump allocator; cnt first: it gets memset) ----
  char* p = (char*)d_ws;
  auto alloc = [&](size_t bytes) -> void* {
    void* r = (void*)p;
    p += (bytes + 255) & ~(size_t)255;
    return r;
  };
  int* cnt     = (int*)alloc(18432 * sizeof(int));
  int* rowptr  = (int*)alloc(18438 * sizeof(int));
  int* cursor  = (int*)alloc(18432 * sizeof(int));
  int* entries = (int*)alloc(655360 * sizeof(int));
  float* Mpp  = (float*)alloc((size_t)NPn * Hh * sizeof(float));
  float* Maa  = (float*)alloc((size_t)NAn * Hh * sizeof(float));
  float* Mpa  = (float*)alloc((size_t)NAn * Hh * sizeof(float));
  float* Map  = (float*)alloc((size_t)NPn * Hh * sizeof(float));
  float* h1p0 = (float*)alloc((size_t)NPn * Hh * sizeof(float));
  float* h1a0 = (float*)alloc((size_t)NAn * Hh * sizeof(float));
  float* h1p1 = (float*)alloc((size_t)NPn * Hh * sizeof(float));
  float* h1a1 = (float*)alloc((size_t)NAn * Hh * sizeof(float));
  float* h2p0 = (float*)alloc((size_t)NPn * Hh * sizeof(float));
  float* h2a0 = (float*)alloc((size_t)NAn * Hh * sizeof(float));
  float* P1pp = (float*)alloc((size_t)NPn * 256 * sizeof(float));
  float* P2pp = (float*)alloc((size_t)NPn * 256 * sizeof(float));
  float* P1aa = (float*)alloc((size_t)NAn * 256 * sizeof(float));
  float* P2aa = (float*)alloc((size_t)NAn * 256 * sizeof(float));

  const int RP_PPD = 0, RP_AAD = 4097, RP_PAD = 6146, RP_APD = 8195;
  const int EN_PPD = 0, EN_AAD = 131072, EN_PAD = 196608, EN_APD = 327680;

  hipMemsetAsync(cnt, 0, 18432 * sizeof(int), stream);
  hist_kernel<<<2560, 256, 0, stream>>>(dst_pp, dst_aa, dst_pa, dst_ap, src_pp, src_aa, cnt);
  scan_kernel<<<6, 256, 0, stream>>>(cnt, rowptr, cursor);
  scatter_kernel<<<2560, 256, 0, stream>>>(src_pp, dst_pp, src_aa, dst_aa,
                                           src_pa, dst_pa, src_ap, dst_ap,
                                           cursor, entries);

  // ---- GNN1 (single=True: pp, aa only) ----
  {
    AggArgs a{};
    a.s[0] = {x_p, nullptr, Mpp, RP_PPD, EN_PPD, 18};
    a.s[1] = {x_a, nullptr, Maa, RP_AAD, EN_AAD, 16};
    a.start[0] = 0; a.start[1] = NPn; a.start[2] = NPn + NAn; a.nseg = 2;
    multi_agg<<<(NPn + NAn) / 8, 256, 0, stream>>>(a, rowptr, entries);
  }
  {
    GArgs g{};
    g.d[0] = {x_p, Wself_p0, Mpp, Wpp0, nullptr, nullptr, h1p0, NPn, 128, 2, 1};
    g.d[1] = {x_a, Wself_a0, Maa, Waa0, nullptr, nullptr, h1a0, NAn, 128, 2, 1};
    g.bstart[0] = 0; g.bstart[1] = 128; g.bstart[2] = 192; g.nd = 2;
    gemm_b<<<192, 256, 0, stream>>>(g);
  }
  {
    AggArgs a{};
    a.s[0] = {h1p0, nullptr, Mpp, RP_PPD, EN_PPD, 18};
    a.s[1] = {h1a0, nullptr, Maa, RP_AAD, EN_AAD, 16};
    a.start[0] = 0; a.start[1] = NPn; a.start[2] = NPn + NAn; a.nseg = 2;
    multi_agg<<<(NPn + NAn) / 8, 256, 0, stream>>>(a, rowptr, entries);
  }
  {
    GArgs g{};
    g.d[0] = {h1p0, Wself_p1, Mpp, Wpp1, nullptr, nullptr, h1p1, NPn, 128, 2, 1};
    g.d[1] = {h1a0, Wself_a1, Maa, Waa1, nullptr, nullptr, h1a1, NAn, 128, 2, 1};
    g.bstart[0] = 0; g.bstart[1] = 128; g.bstart[2] = 192; g.nd = 2;
    gemm_b<<<192, 256, 0, stream>>>(g);
  }

  // ---- edge MLP node projections: concat(h_s,h_d)@Wep1 == P1[s] + P2[d] ----
  {
    GArgs g{};
    g.d[0] = {h1p1, Wep1_pp,             nullptr, nullptr, nullptr, nullptr, P1pp, NPn, 256, 1, 0};
    g.d[1] = {h1p1, Wep1_pp + 128 * 256, nullptr, nullptr, nullptr, nullptr, P2pp, NPn, 256, 1, 0};
    g.d[2] = {h1a1, Wep1_aa,             nullptr, nullptr, nullptr, nullptr, P1aa, NAn, 256, 1, 0};
    g.d[3] = {h1a1, Wep1_aa + 128 * 256, nullptr, nullptr, nullptr, nullptr, P2aa, NAn, 256, 1, 0};
    g.bstart[0] = 0; g.bstart[1] = 256; g.bstart[2] = 512; g.bstart[3] = 640;
    g.bstart[4] = 768; g.nd = 4;
    gemm_b<<<768, 256, 0, stream>>>(g);
  }

  // ---- JAX keys: key(42) -> split -> (kpp, kaa) (partitionable fold-in) ----
  uint32_t kpp0, kpp1, kaa0, kaa1;
  { uint32_t a0 = 0, a1 = 0; tf2x32(0u, 42u, a0, a1); kpp0 = a0; kpp1 = a1; }
  { uint32_t a0 = 0, a1 = 1; tf2x32(0u, 42u, a0, a1); kaa0 = a0; kaa1 = a1; }

  // ---- fused edge-pred + coalesce + gumbel top-5 + w write ----
  row_topk<<<NPn + NAn, 256, 0, stream>>>(P1pp, P2pp, bep1_pp, Wep2_pp, bep2_pp,
                                          P1aa, P2aa, bep1_aa, Wep2_aa, bep2_aa,
                                          rowptr, entries, w_pp_out, w_aa_out,
                                          kpp0, kpp1, kaa0, kaa1);

  // ---- GNN2 layer 0 (all relations; pp/aa with hard attention weights, w==0 skipped) ----
  {
    AggArgs a{};
    a.s[0] = {x_p, w_pp_out, Mpp, RP_PPD, EN_PPD, 18};
    a.s[1] = {x_a, nullptr,  Map, RP_APD, EN_APD, 0};
    a.s[2] = {x_a, w_aa_out, Maa, RP_AAD, EN_AAD, 16};
    a.s[3] = {x_p, nullptr,  Mpa, RP_PAD, EN_PAD, 0};
    a.start[0] = 0; a.start[1] = NPn; a.start[2] = 2 * NPn;
    a.start[3] = 2 * NPn + NAn; a.start[4] = 2 * NPn + 2 * NAn; a.nseg = 4;
    multi_agg<<<(2 * NPn + 2 * NAn) / 8, 256, 0, stream>>>(a, rowptr, entries);
  }
  {
    GArgs g{};
    g.d[0] = {x_p, Wself_p0, Mpp, Wpp0, Map, Wap0, h2p0, NPn, 128, 3, 1};
    g.d[1] = {x_a, Wself_a0, Maa, Waa0, Mpa, Wpa0, h2a0, NAn, 128, 3, 1};
    g.bstart[0] = 0; g.bstart[1] = 128; g.bstart[2] = 192; g.nd = 2;
    gemm_b<<<192, 256, 0, stream>>>(g);
  }

  // ---- GNN2 layer 1 only needed at one paper row -> fused with classifier ----
  final_kernel<<<1, 128, 0, stream>>>(h2p0, h2a0, idxPtr, w_pp_out,
                                      rowptr + RP_PPD, entries + EN_PPD,
                                      rowptr + RP_APD, entries + EN_APD,
                                      Wself_p1, Wpp1, Wap1, Wc, bc, out);
}